// Round 6
// baseline (171.948 us; speedup 1.0000x reference)
//
#include <hip/hip_runtime.h>
#include <math.h>
#include <stdint.h>

// Net_90434831385322: z = A + span*sigmoid(relu((x-A)/span @ W1 + b1) @ W2 + b2)
// BATCH=4194304, OBS=4, HID=64, ACT=4, fp32 in/out.
//
// R5 = R4 with type fix: __builtin_amdgcn_cvt_pkrtz returns __fp16-vec, so
// hf2/hf8 are __fp16 ext-vectors (not _Float16).
//
// R4: move the FMAs off the (saturated ~64/103 TF) fp32 VALU onto the matrix
// pipe via split-f16 3-term MFMA (16x16x32_f16, fp32 accumulate):
//   layer1: h = x@W1' + b1'   as ONE mfma per 16-hid block, K-slots:
//           k0-3: xh*wh, k4-7: xh*wl, k8-11: xl*wh, k12/13: 1.0*b1h/b1l
//   layer2: y = h@W2 + b2     as 6 mfma, K=192: hh*wh, hl*wh, hh*wl
// h repack uses a K-permutation (c = nb*16+i  ->  k = i*4+nb) so each lane's
// 16 h values write LDS as contiguous b64 (no transpose scatter).
// Error budget: residuals 2^-11 (f16), dropped terms ~2^-22 rel -> worst
// dy ~0.03 vs 0.107 budget (threshold 4e-3 on z, span 0.15).

#define BATCH 4194304
#define TPB   256
#define NBLK  (BATCH / TPB)   // 16384 blocks; 1 row/thread, 64 rows/wave

typedef __fp16 hf2 __attribute__((ext_vector_type(2)));
typedef __fp16 hf8 __attribute__((ext_vector_type(8)));
typedef float f4 __attribute__((ext_vector_type(4)));

union FragU { hf8 h; uint4 u4; uint32_t u[4]; };

static __device__ __forceinline__ uint32_t h2bits(hf2 v) {
    union { hf2 h; uint32_t u; } c; c.h = v; return c.u;
}

// ws layout (floats / bytes):
//   bytes [0    .. 4095]  B1 frags  [nb=0..3][lane=0..63] x 16B   (layer1 B)
//   bytes [4096 .. 8191]  B2 frags  [wh0, wh1, wl0, wl1][lane] x 16B
//   float [2048 .. 2063]  b2ext[16] (cols 0-3 = b2, rest 0)
//   float [2064 .. 2079]  span16[16]
//   float [2080 .. 2095]  A16[16]
__global__ __launch_bounds__(256)
void prep_kernel(const float* __restrict__ W1, const float* __restrict__ b1,
                 const float* __restrict__ W2, const float* __restrict__ b2,
                 float* __restrict__ ws) {
    const float LA[4] = {0.001f, 0.02f, 0.05f, 0.001f};
    const float LS[4] = {0.003f, 0.03f, 0.15f, 0.003f};
    const int t = threadIdx.x, lane = t & 63, fid = t >> 6;
    const int q = lane >> 4, i15 = lane & 15;

    // ---- B1 frag fid = hid-block nb: B[n = lane&15][k = q*8+j] ----
    {
        const int n = fid * 16 + i15;
        float wh[4], wl[4];
        float b1p = b1[n];
        for (int k = 0; k < 4; ++k) {
            float w1v = W1[k * 64 + n];
            float w = w1v / LS[k];              // fold input scaling
            b1p -= (LA[k] / LS[k]) * w1v;       // fold into bias
            wh[k] = (float)(_Float16)w;
            wl[k] = w - wh[k];
        }
        float bh = (float)(_Float16)b1p;
        float bl = b1p - bh;
        __fp16 v[8];
        for (int j = 0; j < 8; ++j) {
            int k = q * 8 + j;
            float val = (k < 4) ? wh[k] : (k < 8) ? wl[k - 4] : (k < 12) ? wh[k - 8]
                      : (k == 12) ? bh : (k == 13) ? bl : 0.0f;
            v[j] = (__fp16)val;
        }
        *(uint4*)((char*)ws + (fid * 64 + lane) * 16) = *(uint4*)v;
    }
    // ---- B2 frag fid: {wh seg0, wh seg1, wl seg0, wl seg1} ----
    // A's k-slot for hid c is k = (c&15)*4 + (c>>4)  =>  c(k) = (k&3)*16 + (k>>2)
    {
        const int n = i15, seg = fid & 1, lo = fid >> 1;
        __fp16 v[8];
        for (int j = 0; j < 8; ++j) {
            int k = seg * 32 + q * 8 + j;
            int c = (k & 3) * 16 + (k >> 2);
            float val = 0.0f;
            if (n < 4) {
                float w = W2[c * 4 + n];
                float wh = (float)(_Float16)w;
                val = lo ? (w - wh) : wh;
            }
            v[j] = (__fp16)val;
        }
        *(uint4*)((char*)ws + 4096 + (fid * 64 + lane) * 16) = *(uint4*)v;
    }
    if (t < 16) {
        ws[2048 + t] = (t < 4) ? b2[t] : 0.0f;
        ws[2064 + t] = (t < 4) ? LS[t] : 0.0f;
        ws[2080 + t] = (t < 4) ? LA[t] : 0.0f;
    }
}

__global__ __launch_bounds__(TPB, 4)
void mlp_kernel(const float* __restrict__ x, const float* __restrict__ ws,
                float* __restrict__ out) {
    // per-wave private LDS regions -> only ONE barrier (after xsplit write);
    // all other LDS RAW hazards are same-wave (lgkmcnt, compiler-inserted).
    __shared__ uint4 xsplit[4][64];                 // 4 KB: [xh01,xh23,xl01,xl23]
    __shared__ __align__(16) char A2[4][16 * 272];  // 17 KB: 16 rows x (hh 128B | hl 128B | pad 16B)
    __shared__ float ybuf[4][64][4];                // 4 KB

    const int tid = threadIdx.x, wid = tid >> 6, lane = tid & 63;
    const int q = tid >> 4 & 3, i15 = tid & 15;
    const long row = (long)blockIdx.x * TPB + tid;

    // constant weight fragments (L2-hot, per-lane 16B loads)
    FragU B1f[4], Bwh[2], Bwl[2];
    #pragma unroll
    for (int nb = 0; nb < 4; ++nb)
        B1f[nb].u4 = *(const uint4*)((const char*)ws + (nb * 64 + lane) * 16);
    #pragma unroll
    for (int s = 0; s < 2; ++s) {
        Bwh[s].u4 = *(const uint4*)((const char*)ws + 4096 + (s * 64 + lane) * 16);
        Bwl[s].u4 = *(const uint4*)((const char*)ws + 4096 + ((2 + s) * 64 + lane) * 16);
    }
    const float b2c = ws[2048 + i15];
    const float spc = ws[2064 + i15];
    const float acn = ws[2080 + i15];

    // x load + split to f16 hi/lo (x in [0,1], residual capture)
    f4 xv = *(const f4*)(x + row * 4);
    hf2 xh01 = __builtin_amdgcn_cvt_pkrtz(xv.x, xv.y);
    hf2 xh23 = __builtin_amdgcn_cvt_pkrtz(xv.z, xv.w);
    hf2 xl01 = __builtin_amdgcn_cvt_pkrtz(xv.x - (float)xh01.x, xv.y - (float)xh01.y);
    hf2 xl23 = __builtin_amdgcn_cvt_pkrtz(xv.z - (float)xh23.x, xv.w - (float)xh23.y);
    uint4 xp;
    xp.x = h2bits(xh01); xp.y = h2bits(xh23);
    xp.z = h2bits(xl01); xp.w = h2bits(xl23);
    xsplit[wid][lane] = xp;
    __syncthreads();

    const uint32_t ONE2 = 0x3C003C00u;   // {1.0h, 1.0h} -> pairs with b1h/b1l
    char* a2p = A2[wid];

    #pragma unroll 1
    for (int t = 0; t < 4; ++t) {
        // A1 frag: q0 = [xh,xh], q1 = [xl, 1,1,0,0], q2/q3 = 0
        uint4 xs = xsplit[wid][t * 16 + i15];
        FragU a1;
        a1.u[0] = q == 0 ? xs.x : (q == 1 ? xs.z : 0u);
        a1.u[1] = q == 0 ? xs.y : (q == 1 ? xs.w : 0u);
        a1.u[2] = q == 0 ? xs.x : (q == 1 ? ONE2 : 0u);
        a1.u[3] = q == 0 ? xs.y : 0u;

        f4 c1[4];
        #pragma unroll
        for (int nb = 0; nb < 4; ++nb) {
            f4 z4 = {0.0f, 0.0f, 0.0f, 0.0f};
            c1[nb] = __builtin_amdgcn_mfma_f32_16x16x32_f16(a1.h, B1f[nb].h, z4, 0, 0, 0);
        }
        // relu
        #pragma unroll
        for (int nb = 0; nb < 4; ++nb)
            #pragma unroll
            for (int r = 0; r < 4; ++r)
                c1[nb][r] = fmaxf(c1[nb][r], 0.0f);

        // split h -> f16 hi/lo, write permuted-K rows: lane i writes k=i*4+nb
        #pragma unroll
        for (int r = 0; r < 4; ++r) {
            const int m2 = q * 4 + r;
            hf2 hhA = __builtin_amdgcn_cvt_pkrtz(c1[0][r], c1[1][r]);
            hf2 hhB = __builtin_amdgcn_cvt_pkrtz(c1[2][r], c1[3][r]);
            hf2 hlA = __builtin_amdgcn_cvt_pkrtz(c1[0][r] - (float)hhA.x,
                                                 c1[1][r] - (float)hhA.y);
            hf2 hlB = __builtin_amdgcn_cvt_pkrtz(c1[2][r] - (float)hhB.x,
                                                 c1[3][r] - (float)hhB.y);
            *(uint2*)(a2p + m2 * 272 + i15 * 8)       = make_uint2(h2bits(hhA), h2bits(hhB));
            *(uint2*)(a2p + m2 * 272 + 128 + i15 * 8) = make_uint2(h2bits(hlA), h2bits(hlB));
        }

        // layer2 A frags (b128, +16B row pad -> 2-way banks, conflict-free)
        FragU af0, af1, af2, af3;
        af0.u4 = *(const uint4*)(a2p + i15 * 272 + q * 16);        // hh k0-31
        af1.u4 = *(const uint4*)(a2p + i15 * 272 + 64 + q * 16);   // hh k32-63
        af2.u4 = *(const uint4*)(a2p + i15 * 272 + 128 + q * 16);  // hl k0-31
        af3.u4 = *(const uint4*)(a2p + i15 * 272 + 192 + q * 16);  // hl k32-63

        f4 acc = {b2c, b2c, b2c, b2c};
        acc = __builtin_amdgcn_mfma_f32_16x16x32_f16(af0.h, Bwh[0].h, acc, 0, 0, 0);
        acc = __builtin_amdgcn_mfma_f32_16x16x32_f16(af1.h, Bwh[1].h, acc, 0, 0, 0);
        acc = __builtin_amdgcn_mfma_f32_16x16x32_f16(af2.h, Bwh[0].h, acc, 0, 0, 0);
        acc = __builtin_amdgcn_mfma_f32_16x16x32_f16(af3.h, Bwh[1].h, acc, 0, 0, 0);
        acc = __builtin_amdgcn_mfma_f32_16x16x32_f16(af0.h, Bwl[0].h, acc, 0, 0, 0);
        acc = __builtin_amdgcn_mfma_f32_16x16x32_f16(af1.h, Bwl[1].h, acc, 0, 0, 0);

        // epilogue: z = A_c + span_c * sigmoid(y), cols 0-3 only
        if (i15 < 4) {
            #pragma unroll
            for (int r = 0; r < 4; ++r) {
                float zz = fmaf(spc, 1.0f / (1.0f + __expf(-acc[r])), acn);
                ybuf[wid][t * 16 + q * 4 + r][i15] = zz;
            }
        }
    }

    // coalesced float4 store via ybuf round-trip
    f4 zr = *(const f4*)&ybuf[wid][lane][0];
    *(f4*)(out + row * 4) = zr;
}

extern "C" void kernel_launch(void* const* d_in, const int* in_sizes, int n_in,
                              void* d_out, int out_size, void* d_ws, size_t ws_size,
                              hipStream_t stream) {
    const float* x  = (const float*)d_in[0];
    const float* W1 = (const float*)d_in[1];
    const float* b1 = (const float*)d_in[2];
    const float* W2 = (const float*)d_in[3];
    const float* b2 = (const float*)d_in[4];
    float* out = (float*)d_out;
    float* ws  = (float*)d_ws;

    prep_kernel<<<1, 256, 0, stream>>>(W1, b1, W2, b2, ws);
    mlp_kernel<<<NBLK, TPB, 0, stream>>>(x, ws, out);
}

// Round 7
// 153.981 us; speedup vs baseline: 1.1167x; 1.1167x over previous
//
#include <hip/hip_runtime.h>
#include <math.h>
#include <stdint.h>

// Net_90434831385322: z = A + span*sigmoid(relu((x-A)/span @ W1 + b1) @ W2 + b2)
// BATCH=4194304, OBS=4, HID=64, ACT=4, fp32 in/out.
//
// R7: transposed layer1 kills the LDS transpose (R6: 8-way-conflicted A2
// region, 5.24M conflict cycles, VALU 88%).
//  layer1 (K=16 mfma_f32_16x16x16f16): A=W1-aug [m=hid-in-block][k],
//    B=x-aug [n=row][k]; slots q0: wh*xh, q1: wh*xl, q2: wl*xh, q3: b1h,b1l * 1,1.
//    -> C1: lane (q,i15) holds h[hid=16nb+4q+r][row=i15]: 16 hids of ONE row.
//  layer2 (K=32 f16 x6, 3-term split): A-frags built IN REGISTERS from C1 via
//    pkrtz with baked K-permutation hid(k) = (k&3)*16 + q*4 + seg*2 + ((k>>2)&1).
//  epilogue: rcpf instead of fp32 div. All LDS wave-private, 1 barrier.

#define BATCH 4194304
#define TPB   256
#define NBLK  (BATCH / TPB)   // 16384 blocks; 64 rows/wave, 4 tiles of 16

typedef __fp16 hf2 __attribute__((ext_vector_type(2)));
typedef __fp16 hf4 __attribute__((ext_vector_type(4)));
typedef __fp16 hf8 __attribute__((ext_vector_type(8)));
typedef float  f4  __attribute__((ext_vector_type(4)));

union Frag8 { hf8 h; uint4 u4; uint32_t u[4]; };
union Frag4 { hf4 h; uint2 u2; uint32_t u[2]; };

static __device__ __forceinline__ uint32_t h2bits(hf2 v) {
    union { hf2 h; uint32_t u; } c; c.h = v; return c.u;
}

// ws float layout:
//   [0   .. 511]   A1 frags (K16): [nb=0..3][lane] x 8B
//   [512 ..1535]   B2 frags (K32): [0=wh_s0,1=wh_s1,2=wl_s0,3=wl_s1][lane] x 16B
//   [1536..1551]   b2ext[16];  [1552..1567] span16;  [1568..1583] A16
__global__ __launch_bounds__(256)
void prep_kernel(const float* __restrict__ W1, const float* __restrict__ b1,
                 const float* __restrict__ W2, const float* __restrict__ b2,
                 float* __restrict__ ws) {
    const float LA[4] = {0.001f, 0.02f, 0.05f, 0.001f};
    const float LS[4] = {0.003f, 0.03f, 0.15f, 0.003f};
    const int t = threadIdx.x, lane = t & 63, fid = t >> 6;
    const int q = lane >> 4, i15 = lane & 15;

    // ---- A1 frag, hid-block nb=fid: A[m=i15][k=q*4+j] ----
    {
        const int hid = fid * 16 + i15;
        float b1p = b1[hid];
        float wh[4], wl[4];
        for (int k = 0; k < 4; ++k) {
            float w1v = W1[k * 64 + hid];
            float w = w1v / LS[k];              // fold input scaling
            b1p -= (LA[k] / LS[k]) * w1v;       // fold into bias
            wh[k] = (float)(_Float16)w;
            wl[k] = w - wh[k];
        }
        float bh = (float)(_Float16)b1p;
        float bl = b1p - bh;
        __fp16 v[4];
        for (int j = 0; j < 4; ++j) {
            float val;
            if (q <= 1)      val = wh[j];                     // k0-7: wh (x xh, xl)
            else if (q == 2) val = wl[j];                     // k8-11: wl (x xh)
            else             val = (j == 0) ? bh : (j == 1) ? bl : 0.0f;  // k12-15
            v[j] = (__fp16)val;
        }
        *(uint2*)((char*)ws + (fid * 64 + lane) * 8) = *(uint2*)v;
    }
    // ---- B2 frag: fid: 0=wh seg0, 1=wh seg1, 2=wl seg0, 3=wl seg1 ----
    // K-permutation matching C1 register holdings:
    //   hid(seg,q,j) = (j&3)*16 + q*4 + seg*2 + (j>>2)
    {
        const int seg = fid & 1, lo = fid >> 1, n = i15;
        __fp16 v[8];
        for (int j = 0; j < 8; ++j) {
            int hid = (j & 3) * 16 + q * 4 + seg * 2 + (j >> 2);
            float val = 0.0f;
            if (n < 4) {
                float w  = W2[hid * 4 + n];
                float wh = (float)(_Float16)w;
                val = lo ? (w - wh) : wh;
            }
            v[j] = (__fp16)val;
        }
        *(uint4*)((char*)ws + 2048 + (fid * 64 + lane) * 16) = *(uint4*)v;
    }
    if (t < 16) {
        ws[1536 + t] = (t < 4) ? b2[t] : 0.0f;
        ws[1552 + t] = (t < 4) ? LS[t] : 0.0f;
        ws[1568 + t] = (t < 4) ? LA[t] : 0.0f;
    }
}

__global__ __launch_bounds__(TPB, 6)
void mlp_kernel(const float* __restrict__ x, const float* __restrict__ ws,
                float* __restrict__ out) {
    // All LDS regions are wave-private (written and read by the same wave).
    // xprep: per row 48B: [xh01 xh23 | xl01 xl23 | xh01 xh23 | ONE2 0] (+16B pad/row? no: 48B = 6 dwords exactly 3x16B... layout: v0 v1 at +0 (16B), v2 v3 at +16 (16B), pad 16B)
    __shared__ __align__(16) char  xprep[4][3072];   // 4 waves x 4 tiles x 16 rows x 48B
    __shared__ __align__(16) float ybuf[4][64][4];   // 4 KB

    const int tid = threadIdx.x, w = tid >> 6, lane = tid & 63;
    const int q = (tid >> 4) & 3, i15 = tid & 15;
    const long row = (long)blockIdx.x * TPB + tid;

    // ---- weights (L2-hot, coalesced per-lane loads) ----
    Frag4 A1[4];
    #pragma unroll
    for (int nb = 0; nb < 4; ++nb)
        A1[nb].u2 = *(const uint2*)((const char*)ws + (nb * 64 + lane) * 8);
    Frag8 Bwh[2], Bwl[2];
    #pragma unroll
    for (int s = 0; s < 2; ++s) {
        Bwh[s].u4 = *(const uint4*)((const char*)ws + 2048 + (s * 64 + lane) * 16);
        Bwl[s].u4 = *(const uint4*)((const char*)ws + 2048 + ((2 + s) * 64 + lane) * 16);
    }
    const float b2c = ws[1536 + i15];
    const float spc = ws[1552 + i15];
    const float acn = ws[1568 + i15];

    // ---- x load + f16 hi/lo split -> xprep (wave-private) ----
    f4 xv = *(const f4*)(x + row * 4);
    hf2 xh01 = __builtin_amdgcn_cvt_pkrtz(xv.x, xv.y);
    hf2 xh23 = __builtin_amdgcn_cvt_pkrtz(xv.z, xv.w);
    hf2 xl01 = __builtin_amdgcn_cvt_pkrtz(xv.x - (float)xh01.x, xv.y - (float)xh01.y);
    hf2 xl23 = __builtin_amdgcn_cvt_pkrtz(xv.z - (float)xh23.x, xv.w - (float)xh23.y);
    const uint32_t ONE2 = 0x3C003C00u;   // {1.0h, 1.0h}
    {
        char* wp = xprep[w] + (lane >> 4) * 768 + (lane & 15) * 48;
        uint4 v01 = make_uint4(h2bits(xh01), h2bits(xh23), h2bits(xl01), h2bits(xl23));
        uint4 v23 = make_uint4(h2bits(xh01), h2bits(xh23), ONE2, 0u);
        *(uint4*)(wp)      = v01;   // q0 reads +0 (xh), q1 reads +8 (xl)
        *(uint4*)(wp + 16) = v23;   // q2 reads +16 (xh), q3 reads +24 (ones)
    }
    __syncthreads();

    const char* xrd = xprep[w] + i15 * 48 + q * 8;
    const f4 zero4 = {0.0f, 0.0f, 0.0f, 0.0f};

    #pragma unroll
    for (int t = 0; t < 4; ++t) {
        // layer1: B-frag = this lane's q-variant of row i15 (tile t)
        Frag4 bfrag;
        bfrag.u2 = *(const uint2*)(xrd + t * 768);
        f4 c1[4];
        #pragma unroll
        for (int nb = 0; nb < 4; ++nb)
            c1[nb] = __builtin_amdgcn_mfma_f32_16x16x16f16(A1[nb].h, bfrag.h, zero4, 0, 0, 0);

        // relu; lane now holds h[hid = 16nb + 4q + r][row = i15]
        #pragma unroll
        for (int nb = 0; nb < 4; ++nb)
            #pragma unroll
            for (int r = 0; r < 4; ++r)
                c1[nb][r] = fmaxf(c1[nb][r], 0.0f);

        // in-register split+pack into layer2 A-frags (permuted K, no LDS!)
        hf2 p01[4], p23[4], l01[4], l23[4];
        #pragma unroll
        for (int r = 0; r < 4; ++r) {
            p01[r] = __builtin_amdgcn_cvt_pkrtz(c1[0][r], c1[1][r]);
            p23[r] = __builtin_amdgcn_cvt_pkrtz(c1[2][r], c1[3][r]);
            l01[r] = __builtin_amdgcn_cvt_pkrtz(c1[0][r] - (float)p01[r].x,
                                                c1[1][r] - (float)p01[r].y);
            l23[r] = __builtin_amdgcn_cvt_pkrtz(c1[2][r] - (float)p23[r].x,
                                                c1[3][r] - (float)p23[r].y);
        }
        Frag8 afh[2], afl[2];
        #pragma unroll
        for (int s = 0; s < 2; ++s) {
            afh[s].u4 = make_uint4(h2bits(p01[2*s]), h2bits(p23[2*s]),
                                   h2bits(p01[2*s+1]), h2bits(p23[2*s+1]));
            afl[s].u4 = make_uint4(h2bits(l01[2*s]), h2bits(l23[2*s]),
                                   h2bits(l01[2*s+1]), h2bits(l23[2*s+1]));
        }

        // layer2: 3-term split, 6 x K=32 MFMA
        f4 acc = {b2c, b2c, b2c, b2c};
        acc = __builtin_amdgcn_mfma_f32_16x16x32_f16(afh[0].h, Bwh[0].h, acc, 0, 0, 0);
        acc = __builtin_amdgcn_mfma_f32_16x16x32_f16(afh[1].h, Bwh[1].h, acc, 0, 0, 0);
        acc = __builtin_amdgcn_mfma_f32_16x16x32_f16(afl[0].h, Bwh[0].h, acc, 0, 0, 0);
        acc = __builtin_amdgcn_mfma_f32_16x16x32_f16(afl[1].h, Bwh[1].h, acc, 0, 0, 0);
        acc = __builtin_amdgcn_mfma_f32_16x16x32_f16(afh[0].h, Bwl[0].h, acc, 0, 0, 0);
        acc = __builtin_amdgcn_mfma_f32_16x16x32_f16(afh[1].h, Bwl[1].h, acc, 0, 0, 0);

        // epilogue: z = A_c + span_c * sigmoid(y); lane holds rows q*4+r, col i15
        if (i15 < 4) {
            #pragma unroll
            for (int r = 0; r < 4; ++r) {
                float e  = __expf(-acc[r]);
                float sg = __builtin_amdgcn_rcpf(1.0f + e);
                ybuf[w][t * 16 + q * 4 + r][i15] = fmaf(spc, sg, acn);
            }
        }
    }

    // same-wave LDS round-trip (lgkmcnt-ordered), coalesced b128 store
    f4 zr = *(const f4*)&ybuf[w][lane][0];
    *(f4*)(out + row * 4) = zr;
}

extern "C" void kernel_launch(void* const* d_in, const int* in_sizes, int n_in,
                              void* d_out, int out_size, void* d_ws, size_t ws_size,
                              hipStream_t stream) {
    const float* x  = (const float*)d_in[0];
    const float* W1 = (const float*)d_in[1];
    const float* b1 = (const float*)d_in[2];
    const float* W2 = (const float*)d_in[3];
    const float* b2 = (const float*)d_in[4];
    float* out = (float*)d_out;
    float* ws  = (float*)d_ws;

    prep_kernel<<<1, 256, 0, stream>>>(W1, b1, W2, b2, ws);
    mlp_kernel<<<NBLK, TPB, 0, stream>>>(x, ws, out);
}